// Round 4
// baseline (295.469 us; speedup 1.0000x reference)
//
#include <hip/hip_runtime.h>
#include <hip/hip_bf16.h>
#include <math.h>

#define TT 8192
#define DD 512
#define HH 1024
#define EE 16
#define NSLOT 18432   // 144 * 128 max padded slots
#define MAXTILES 144
#define BM 128

typedef __attribute__((ext_vector_type(8))) short bf16x8;
typedef __attribute__((ext_vector_type(4))) float f32x4;

__device__ __forceinline__ unsigned short f2bf(float f) {
  union { float f; unsigned u; } v; v.f = f;
  unsigned r = v.u + 0x7fffu + ((v.u >> 16) & 1u);
  return (unsigned short)(r >> 16);
}

__device__ __forceinline__ float bf2f(unsigned short u) {
  union { unsigned u; float f; } v; v.u = ((unsigned)u) << 16;
  return v.f;
}

__device__ __forceinline__ void gload16(const void* g, void* l) {
  __builtin_amdgcn_global_load_lds(
      (const __attribute__((address_space(1))) unsigned int*)g,
      (__attribute__((address_space(3))) unsigned int*)l, 16, 0, 0);
}

// ------- transpose+convert: in f32 [nmat][R][C] -> out bf16 [nmat][C][R] -------
__global__ __launch_bounds__(256) void transpose_cv_kernel(
    const float* __restrict__ in, unsigned short* __restrict__ out, int R, int C) {
  int mat = blockIdx.z;
  int c0 = blockIdx.x * 64;
  int r0 = blockIdx.y * 64;
  const float* src = in + (size_t)mat * R * C;
  unsigned short* dst = out + (size_t)mat * R * C;
  __shared__ unsigned short t[64][68];
  int tid = threadIdx.x;
#pragma unroll
  for (int p = 0; p < 4; p++) {
    int r = tid >> 2;
    int c4 = (tid & 3) + p * 4;
    float4 v = *(const float4*)(src + (size_t)(r0 + r) * C + c0 + c4 * 4);
    t[c4 * 4 + 0][r] = f2bf(v.x);
    t[c4 * 4 + 1][r] = f2bf(v.y);
    t[c4 * 4 + 2][r] = f2bf(v.z);
    t[c4 * 4 + 3][r] = f2bf(v.w);
  }
  __syncthreads();
#pragma unroll
  for (int p = 0; p < 4; p++) {
    int oc = (tid >> 4) + p * 16;
    int ch = tid & 15;
    ushort4 v = *(ushort4*)(&t[oc][ch * 4]);
    *(ushort4*)(dst + (size_t)(c0 + oc) * R + r0 + ch * 4) = v;
  }
}

// ---------------- fused convert + gate ----------------
// 1024 blocks x 8 tokens. Stage Wg [512][16] (32KB) + x rows [8][520] (16.25KB)
// in LDS; emit xb bf16 during staging. Thread = (token, expert, d-half):
// 4 independent f64 accumulators over 256 MACs; d-half combined via
// shfl_xor(32); top-2 via shfl broadcast. All LDS reads <=2-way (free).
__global__ __launch_bounds__(256) void gatecv_kernel(
    const float* __restrict__ x, const float* __restrict__ Wg,
    const float* __restrict__ bg, unsigned short* __restrict__ xb,
    int* __restrict__ gate_e, float* __restrict__ gate_w,
    int* __restrict__ counts) {
  __shared__ float wg_s[DD][EE];   // 32 KB
  __shared__ float x_s[8][520];    // 16.25 KB (pad 8 words -> 2-way max)
  int tid = threadIdx.x;
  int tok0 = blockIdx.x * 8;
#pragma unroll
  for (int p = 0; p < 8; p++) {
    int idx = p * 256 + tid;
    ((float4*)wg_s)[idx] = ((const float4*)Wg)[idx];
  }
#pragma unroll
  for (int p = 0; p < 4; p++) {
    int f = p * 256 + tid;           // token = f>>7, float4-in-row = f&127
    float4 v = ((const float4*)(x + (size_t)tok0 * DD))[f];
    *(float4*)&x_s[f >> 7][(f & 127) * 4] = v;
    ushort4 u;
    u.x = f2bf(v.x); u.y = f2bf(v.y); u.z = f2bf(v.z); u.w = f2bf(v.w);
    ((ushort4*)(xb + (size_t)tok0 * DD))[f] = u;
  }
  __syncthreads();
  int wv = tid >> 6, lane = tid & 63;
  int e = lane & 15, tl = (lane >> 4) & 1, ck = lane >> 5;
  int t = wv * 2 + tl;
  const float* xr = &x_s[t][ck * 256];
  double a0 = 0.0, a1 = 0.0, a2 = 0.0, a3 = 0.0;
#pragma unroll 8
  for (int i = 0; i < 64; i++) {
    float4 xv = *(const float4*)&xr[i * 4];
    int d = ck * 256 + i * 4;
    a0 += (double)xv.x * (double)wg_s[d + 0][e];
    a1 += (double)xv.y * (double)wg_s[d + 1][e];
    a2 += (double)xv.z * (double)wg_s[d + 2][e];
    a3 += (double)xv.w * (double)wg_s[d + 3][e];
  }
  double acc = (a0 + a1) + (a2 + a3);
  acc += __shfl_xor(acc, 32);      // combine d-halves
  float lf = (float)(acc + (double)bg[e]);
  float v1 = -1e30f, v2 = -1e30f;
  int i1 = 0, i2 = 0;
#pragma unroll
  for (int q = 0; q < EE; q++) {
    float v = __shfl(lf, (lane & 16) | q);
    if (v > v1) { v2 = v1; i2 = i1; v1 = v; i1 = q; }
    else if (v > v2) { v2 = v; i2 = q; }
  }
  if (lane == 0 || lane == 16) {
    int t2 = tok0 + t;
    float p = expf(v2 - v1);
    float s = 1.0f / (1.0f + p);
    gate_e[t2 * 2] = i1;
    gate_e[t2 * 2 + 1] = i2;
    gate_w[t2 * 2] = s;
    gate_w[t2 * 2 + 1] = p * s;
    atomicAdd(&counts[i1], 1);
    atomicAdd(&counts[i2], 1);
  }
}

// ---------------- scan: offsets + tile map + slot_token init ----------------
__global__ __launch_bounds__(256) void scan_kernel(
    const int* __restrict__ counts, int* __restrict__ offs,
    int* __restrict__ tile_expert, int* __restrict__ ntiles,
    int* __restrict__ fill, int* __restrict__ slot_token) {
  int tid = threadIdx.x;
  for (int i = tid; i < NSLOT; i += 256) slot_token[i] = -1;
  if (tid == 0) {
    int off = 0, nt = 0;
    for (int e = 0; e < EE; e++) {
      offs[e] = off;
      fill[e] = 0;
      int tiles = (counts[e] + BM - 1) / BM;
      for (int t = 0; t < tiles; t++) tile_expert[nt++] = e;
      off += tiles * BM;
    }
    offs[EE] = off;
    ntiles[0] = nt;
  }
}

// ---------------- scatter tokens to slots ----------------
__global__ __launch_bounds__(256) void scatter_kernel(
    const int* __restrict__ gate_e, const float* __restrict__ gate_w,
    const int* __restrict__ offs, int* __restrict__ fill,
    int* __restrict__ slot_token, float* __restrict__ slot_w,
    int* __restrict__ slot_of) {
  int t = blockIdx.x * blockDim.x + threadIdx.x;
  if (t >= TT) return;
#pragma unroll
  for (int k = 0; k < 2; k++) {
    int e = gate_e[t * 2 + k];
    int pos = atomicAdd(&fill[e], 1);
    int slot = offs[e] + pos;
    slot_token[slot] = t;
    slot_w[slot] = gate_w[t * 2 + k];
    slot_of[t * 2 + k] = slot;
  }
}

// ---------------- GEMM1: h = gelu(x[slot] @ W1[e] + b1[e]) ----------------
__global__ __launch_bounds__(256) void gemm1_kernel(
    const unsigned short* __restrict__ xb, const unsigned short* __restrict__ w1t,
    const float* __restrict__ b1, const int* __restrict__ slot_token,
    const int* __restrict__ tile_expert, const int* __restrict__ ntiles,
    unsigned short* __restrict__ hb) {
  int mt = blockIdx.x;
  if (mt >= ntiles[0]) return;
  int e = tile_expert[mt];
  int row0 = mt * BM;
  int n0 = blockIdx.y * 128;
  __shared__ unsigned short As[128][32];
  __shared__ unsigned short Bs[128][32];
  int tid = threadIdx.x;
  int lane = tid & 63;
  int wave = tid >> 6;
  int wm = wave >> 1, wn = wave & 1;
  int ra = tid >> 2, c = tid & 3;
  int tok_a = slot_token[row0 + ra]; if (tok_a < 0) tok_a = 0;
  int tok_b = slot_token[row0 + ra + 64]; if (tok_b < 0) tok_b = 0;
  const unsigned short* wbase = w1t + ((size_t)e * HH * DD);
  f32x4 acc[4][4];
#pragma unroll
  for (int m = 0; m < 4; m++)
#pragma unroll
    for (int n = 0; n < 4; n++) {
      f32x4 z = {0.f, 0.f, 0.f, 0.f};
      acc[m][n] = z;
    }
  for (int kk = 0; kk < DD / 32; kk++) {
    int k0 = kk * 32;
    __syncthreads();
    gload16(xb + (size_t)tok_a * DD + k0 + c * 8, &As[ra][c * 8]);
    gload16(xb + (size_t)tok_b * DD + k0 + c * 8, &As[ra + 64][c * 8]);
    gload16(wbase + (size_t)(n0 + ra) * DD + k0 + c * 8, &Bs[ra][c * 8]);
    gload16(wbase + (size_t)(n0 + ra + 64) * DD + k0 + c * 8, &Bs[ra + 64][c * 8]);
    __syncthreads();
    bf16x8 a[4], b[4];
#pragma unroll
    for (int m = 0; m < 4; m++)
      a[m] = *(const bf16x8*)(&As[wm * 64 + m * 16 + (lane & 15)][(lane >> 4) * 8]);
#pragma unroll
    for (int n = 0; n < 4; n++)
      b[n] = *(const bf16x8*)(&Bs[wn * 64 + n * 16 + (lane & 15)][(lane >> 4) * 8]);
#pragma unroll
    for (int m = 0; m < 4; m++)
#pragma unroll
      for (int n = 0; n < 4; n++)
        acc[m][n] = __builtin_amdgcn_mfma_f32_16x16x32_bf16(a[m], b[n], acc[m][n], 0, 0, 0);
  }
  const float* b1e = b1 + (size_t)e * HH;
#pragma unroll
  for (int m = 0; m < 4; m++) {
#pragma unroll
    for (int r = 0; r < 4; r++) {
      int slot = row0 + wm * 64 + m * 16 + ((lane >> 4) << 2) + r;
      unsigned short* hrow = hb + (size_t)slot * HH;
#pragma unroll
      for (int n = 0; n < 4; n++) {
        int hc = n0 + wn * 64 + n * 16 + (lane & 15);
        float v = acc[m][n][r] + b1e[hc];
        v = 0.5f * v * (1.0f + erff(v * 0.70710678118654752f));
        hrow[hc] = f2bf(v);
      }
    }
  }
}

// ---------------- GEMM2: yw[slot] = w*(h[slot] @ W2[e] + b2[e])  (USE_Y)
//                  or    out[tok] += w*(...) via atomics          (fallback)
template <int USE_Y>
__global__ __launch_bounds__(256) void gemm2_kernel(
    const unsigned short* __restrict__ hb, const unsigned short* __restrict__ w2t,
    const float* __restrict__ b2, const int* __restrict__ slot_token,
    const float* __restrict__ slot_w, const int* __restrict__ tile_expert,
    const int* __restrict__ ntiles, unsigned short* __restrict__ yw,
    float* __restrict__ out) {
  int mt = blockIdx.x;
  if (mt >= ntiles[0]) return;
  int e = tile_expert[mt];
  int row0 = mt * BM;
  int n0 = blockIdx.y * 128;
  __shared__ unsigned short As[128][32];
  __shared__ unsigned short Bs[128][32];
  int tid = threadIdx.x;
  int lane = tid & 63;
  int wave = tid >> 6;
  int wm = wave >> 1, wn = wave & 1;
  int ra = tid >> 2, c = tid & 3;
  const unsigned short* wbase = w2t + ((size_t)e * DD * HH);
  f32x4 acc[4][4];
#pragma unroll
  for (int m = 0; m < 4; m++)
#pragma unroll
    for (int n = 0; n < 4; n++) {
      f32x4 z = {0.f, 0.f, 0.f, 0.f};
      acc[m][n] = z;
    }
  for (int kk = 0; kk < HH / 32; kk++) {
    int k0 = kk * 32;
    __syncthreads();
    gload16(hb + (size_t)(row0 + ra) * HH + k0 + c * 8, &As[ra][c * 8]);
    gload16(hb + (size_t)(row0 + ra + 64) * HH + k0 + c * 8, &As[ra + 64][c * 8]);
    gload16(wbase + (size_t)(n0 + ra) * HH + k0 + c * 8, &Bs[ra][c * 8]);
    gload16(wbase + (size_t)(n0 + ra + 64) * HH + k0 + c * 8, &Bs[ra + 64][c * 8]);
    __syncthreads();
    bf16x8 a[4], b[4];
#pragma unroll
    for (int m = 0; m < 4; m++)
      a[m] = *(const bf16x8*)(&As[wm * 64 + m * 16 + (lane & 15)][(lane >> 4) * 8]);
#pragma unroll
    for (int n = 0; n < 4; n++)
      b[n] = *(const bf16x8*)(&Bs[wn * 64 + n * 16 + (lane & 15)][(lane >> 4) * 8]);
#pragma unroll
    for (int m = 0; m < 4; m++)
#pragma unroll
      for (int n = 0; n < 4; n++)
        acc[m][n] = __builtin_amdgcn_mfma_f32_16x16x32_bf16(a[m], b[n], acc[m][n], 0, 0, 0);
  }
  const float* b2e = b2 + (size_t)e * DD;
#pragma unroll
  for (int m = 0; m < 4; m++) {
#pragma unroll
    for (int r = 0; r < 4; r++) {
      int slot = row0 + wm * 64 + m * 16 + ((lane >> 4) << 2) + r;
      if (USE_Y) {
        float w = slot_w[slot];
        unsigned short* yrow = yw + (size_t)slot * DD;
#pragma unroll
        for (int n = 0; n < 4; n++) {
          int dc = n0 + wn * 64 + n * 16 + (lane & 15);
          yrow[dc] = f2bf(w * (acc[m][n][r] + b2e[dc]));
        }
      } else {
        int tok = slot_token[slot];
        if (tok >= 0) {
          float w = slot_w[slot];
          float* orow = out + (size_t)tok * DD;
#pragma unroll
          for (int n = 0; n < 4; n++) {
            int dc = n0 + wn * 64 + n * 16 + (lane & 15);
            float v = acc[m][n][r] + b2e[dc];
            atomicAdd(&orow[dc], w * v);
          }
        }
      }
    }
  }
}

// ---------------- combine: out[t] = yw[s1] + yw[s2] ----------------
__global__ __launch_bounds__(256) void combine_kernel(
    const unsigned short* __restrict__ yw, const int* __restrict__ slot_of,
    float* __restrict__ out) {
  int gid = blockIdx.x * 256 + threadIdx.x;  // one per 8 outputs
  int t = gid >> 6;
  int d0 = (gid & 63) * 8;
  int s1 = slot_of[t * 2], s2 = slot_of[t * 2 + 1];
  const ushort4* p1 = (const ushort4*)(yw + (size_t)s1 * DD + d0);
  const ushort4* p2 = (const ushort4*)(yw + (size_t)s2 * DD + d0);
  ushort4 a0 = p1[0], a1 = p1[1];
  ushort4 b0 = p2[0], b1 = p2[1];
  float4 o0, o1;
  o0.x = bf2f(a0.x) + bf2f(b0.x);
  o0.y = bf2f(a0.y) + bf2f(b0.y);
  o0.z = bf2f(a0.z) + bf2f(b0.z);
  o0.w = bf2f(a0.w) + bf2f(b0.w);
  o1.x = bf2f(a1.x) + bf2f(b1.x);
  o1.y = bf2f(a1.y) + bf2f(b1.y);
  o1.z = bf2f(a1.z) + bf2f(b1.z);
  o1.w = bf2f(a1.w) + bf2f(b1.w);
  float* orow = out + (size_t)t * DD + d0;
  ((float4*)orow)[0] = o0;
  ((float4*)orow)[1] = o1;
}

extern "C" void kernel_launch(void* const* d_in, const int* in_sizes, int n_in,
                              void* d_out, int out_size, void* d_ws, size_t ws_size,
                              hipStream_t stream) {
  const float* x  = (const float*)d_in[0];
  const float* Wg = (const float*)d_in[1];
  const float* bg = (const float*)d_in[2];
  const float* W1 = (const float*)d_in[3];
  const float* b1 = (const float*)d_in[4];
  const float* W2 = (const float*)d_in[5];
  const float* b2 = (const float*)d_in[6];
  float* out = (float*)d_out;

  uint8_t* w = (uint8_t*)d_ws;
  size_t o = 0;
  unsigned short* xb  = (unsigned short*)(w + o); o += (size_t)TT * DD * 2;       // 8 MB
  unsigned short* w1t = (unsigned short*)(w + o); o += (size_t)EE * DD * HH * 2;  // 16 MB
  unsigned short* w2t = (unsigned short*)(w + o); o += (size_t)EE * DD * HH * 2;  // 16 MB
  unsigned short* hb  = (unsigned short*)(w + o); o += (size_t)NSLOT * HH * 2;    // 37.7 MB
  int*   slot_token = (int*)(w + o);   o += (size_t)NSLOT * 4;
  float* slot_w     = (float*)(w + o); o += (size_t)NSLOT * 4;
  int*   slot_of    = (int*)(w + o);   o += (size_t)TT * 2 * 4;
  int*   gate_e     = (int*)(w + o);   o += (size_t)TT * 2 * 4;
  float* gate_w     = (float*)(w + o); o += (size_t)TT * 2 * 4;
  int*   counts     = (int*)(w + o);   o += 64;
  int*   fill       = (int*)(w + o);   o += 64;
  int*   offs       = (int*)(w + o);   o += 128;
  int*   tile_expert= (int*)(w + o);   o += 640;
  int*   ntiles     = (int*)(w + o);   o += 64;
  unsigned short* yw = (unsigned short*)(w + o);
  size_t need_y = o + (size_t)NSLOT * DD * 2;   // +18.9 MB
  int use_y = (ws_size >= need_y);

  hipMemsetAsync(counts, 0, 64, stream);
  if (!use_y) hipMemsetAsync(d_out, 0, (size_t)TT * DD * 4, stream);

  // W1 [E][D][H] -> w1t [E][H][D]
  {
    dim3 g(HH / 64, DD / 64, EE);
    transpose_cv_kernel<<<g, 256, 0, stream>>>(W1, w1t, DD, HH);
  }
  // W2 [E][H][D] -> w2t [E][D][H]
  {
    dim3 g(DD / 64, HH / 64, EE);
    transpose_cv_kernel<<<g, 256, 0, stream>>>(W2, w2t, HH, DD);
  }
  gatecv_kernel<<<TT / 8, 256, 0, stream>>>(x, Wg, bg, xb, gate_e, gate_w, counts);
  scan_kernel<<<1, 256, 0, stream>>>(counts, offs, tile_expert, ntiles, fill, slot_token);
  scatter_kernel<<<TT / 256, 256, 0, stream>>>(gate_e, gate_w, offs, fill,
                                               slot_token, slot_w, slot_of);
  {
    dim3 g(MAXTILES, HH / 128);
    gemm1_kernel<<<g, 256, 0, stream>>>(xb, w1t, b1, slot_token, tile_expert, ntiles, hb);
  }
  {
    dim3 g(MAXTILES, DD / 128);
    if (use_y)
      gemm2_kernel<1><<<g, 256, 0, stream>>>(hb, w2t, b2, slot_token, slot_w,
                                             tile_expert, ntiles, yw, out);
    else
      gemm2_kernel<0><<<g, 256, 0, stream>>>(hb, w2t, b2, slot_token, slot_w,
                                             tile_expert, ntiles, yw, out);
  }
  if (use_y) {
    combine_kernel<<<TT * (DD / 8) / 256, 256, 0, stream>>>(yw, slot_of, out);
  }
}

// Round 5
// 267.944 us; speedup vs baseline: 1.1027x; 1.1027x over previous
//
#include <hip/hip_runtime.h>
#include <hip/hip_bf16.h>
#include <math.h>

#define TT 8192
#define DD 512
#define HH 1024
#define EE 16
#define NSLOT 18432   // 144 * 128 max padded slots
#define MAXTILES 144
#define BM 128
#define RETRYCAP 1024

typedef __attribute__((ext_vector_type(8))) short bf16x8;
typedef __attribute__((ext_vector_type(4))) float f32x4;

__device__ __forceinline__ unsigned short f2bf(float f) {
  union { float f; unsigned u; } v; v.f = f;
  unsigned r = v.u + 0x7fffu + ((v.u >> 16) & 1u);
  return (unsigned short)(r >> 16);
}

__device__ __forceinline__ float bf2f(unsigned short u) {
  union { unsigned u; float f; } v; v.u = ((unsigned)u) << 16;
  return v.f;
}

__device__ __forceinline__ void gload16(const void* g, void* l) {
  __builtin_amdgcn_global_load_lds(
      (const __attribute__((address_space(1))) unsigned int*)g,
      (__attribute__((address_space(3))) unsigned int*)l, 16, 0, 0);
}

// ------- transpose+convert: in f32 [nmat][R][C] -> out bf16 [nmat][C][R] -------
__global__ __launch_bounds__(256) void transpose_cv_kernel(
    const float* __restrict__ in, unsigned short* __restrict__ out, int R, int C) {
  int mat = blockIdx.z;
  int c0 = blockIdx.x * 64;
  int r0 = blockIdx.y * 64;
  const float* src = in + (size_t)mat * R * C;
  unsigned short* dst = out + (size_t)mat * R * C;
  __shared__ unsigned short t[64][68];
  int tid = threadIdx.x;
#pragma unroll
  for (int p = 0; p < 4; p++) {
    int r = tid >> 2;
    int c4 = (tid & 3) + p * 4;
    float4 v = *(const float4*)(src + (size_t)(r0 + r) * C + c0 + c4 * 4);
    t[c4 * 4 + 0][r] = f2bf(v.x);
    t[c4 * 4 + 1][r] = f2bf(v.y);
    t[c4 * 4 + 2][r] = f2bf(v.z);
    t[c4 * 4 + 3][r] = f2bf(v.w);
  }
  __syncthreads();
#pragma unroll
  for (int p = 0; p < 4; p++) {
    int oc = (tid >> 4) + p * 16;
    int ch = tid & 15;
    ushort4 v = *(ushort4*)(&t[oc][ch * 4]);
    *(ushort4*)(dst + (size_t)(c0 + oc) * R + r0 + ch * 4) = v;
  }
}

// ---------------- fused convert + gate, f32 fast path ----------------
// 1024 blocks x 8 tokens. Same LDS layout as R4 (0 bank conflicts) but pure
// f32 FMAs (no f64, no cvts). Tracks top-3; near-ties (v2-v3 < 1e-3) are
// queued for exact f64 repair in gatefix_kernel.
__global__ __launch_bounds__(256) void gatecv_kernel(
    const float* __restrict__ x, const float* __restrict__ Wg,
    const float* __restrict__ bg, unsigned short* __restrict__ xb,
    int* __restrict__ gate_e, float* __restrict__ gate_w,
    int* __restrict__ nretry, int* __restrict__ retry) {
  __shared__ float wg_s[DD][EE];   // 32 KB
  __shared__ float x_s[8][520];    // 16.25 KB
  int tid = threadIdx.x;
  int tok0 = blockIdx.x * 8;
#pragma unroll
  for (int p = 0; p < 8; p++) {
    int idx = p * 256 + tid;
    ((float4*)wg_s)[idx] = ((const float4*)Wg)[idx];
  }
#pragma unroll
  for (int p = 0; p < 4; p++) {
    int f = p * 256 + tid;
    float4 v = ((const float4*)(x + (size_t)tok0 * DD))[f];
    *(float4*)&x_s[f >> 7][(f & 127) * 4] = v;
    ushort4 u;
    u.x = f2bf(v.x); u.y = f2bf(v.y); u.z = f2bf(v.z); u.w = f2bf(v.w);
    ((ushort4*)(xb + (size_t)tok0 * DD))[f] = u;
  }
  __syncthreads();
  int wv = tid >> 6, lane = tid & 63;
  int e = lane & 15, tl = (lane >> 4) & 1, ck = lane >> 5;
  int t = wv * 2 + tl;
  const float* xr = &x_s[t][ck * 256];
  float a0 = 0.f, a1 = 0.f, a2 = 0.f, a3 = 0.f;
#pragma unroll 8
  for (int i = 0; i < 64; i++) {
    float4 xv = *(const float4*)&xr[i * 4];
    int d = ck * 256 + i * 4;
    a0 += xv.x * wg_s[d + 0][e];
    a1 += xv.y * wg_s[d + 1][e];
    a2 += xv.z * wg_s[d + 2][e];
    a3 += xv.w * wg_s[d + 3][e];
  }
  float acc = (a0 + a1) + (a2 + a3);
  acc += __shfl_xor(acc, 32);      // combine d-halves
  float lf = acc + bg[e];
  float v1 = -1e30f, v2 = -1e30f, v3 = -1e30f;
  int i1 = 0, i2 = 0;
#pragma unroll
  for (int q = 0; q < EE; q++) {
    float v = __shfl(lf, (lane & 16) | q);
    if (v > v1) { v3 = v2; v2 = v1; i2 = i1; v1 = v; i1 = q; }
    else if (v > v2) { v3 = v2; v2 = v; i2 = q; }
    else if (v > v3) { v3 = v; }
  }
  if (lane == 0 || lane == 16) {
    int t2 = tok0 + t;
    float p = expf(v2 - v1);
    float s = 1.0f / (1.0f + p);
    gate_e[t2 * 2] = i1;
    gate_e[t2 * 2 + 1] = i2;
    gate_w[t2 * 2] = s;
    gate_w[t2 * 2 + 1] = p * s;
    if (v2 - v3 < 1e-3f) {
      int pos = atomicAdd(nretry, 1);
      if (pos < RETRYCAP) retry[pos] = t2;
    }
  }
}

// ---------------- gatefix: exact f64 recompute for near-tie tokens ----------------
// 64 blocks x 16 tokens/block; thread = (token-slot, expert). Selection
// semantics identical to the f64 gate that passed rounds 1-4.
__global__ __launch_bounds__(256) void gatefix_kernel(
    const float* __restrict__ x, const float* __restrict__ Wg,
    const float* __restrict__ bg, const int* __restrict__ nretry,
    const int* __restrict__ retry, int* __restrict__ gate_e,
    float* __restrict__ gate_w) {
  __shared__ float lg[16][17];
  __shared__ int toks[16];
  int tid = threadIdx.x;
  int sl = tid >> 4, e = tid & 15;
  int s = blockIdx.x * 16 + sl;
  int n = *nretry; if (n > RETRYCAP) n = RETRYCAP;
  int active = (s < n);
  int tok = 0;
  if (active) tok = retry[s];
  if (active) {
    const float* xr = x + (size_t)tok * DD;
    double a0 = 0.0, a1 = 0.0, a2 = 0.0, a3 = 0.0;
    for (int i = 0; i < DD / 4; i++) {
      a0 += (double)xr[i * 4 + 0] * (double)Wg[(i * 4 + 0) * EE + e];
      a1 += (double)xr[i * 4 + 1] * (double)Wg[(i * 4 + 1) * EE + e];
      a2 += (double)xr[i * 4 + 2] * (double)Wg[(i * 4 + 2) * EE + e];
      a3 += (double)xr[i * 4 + 3] * (double)Wg[(i * 4 + 3) * EE + e];
    }
    double acc = (a0 + a1) + (a2 + a3);
    lg[sl][e] = (float)(acc + (double)bg[e]);
    toks[sl] = tok;
  }
  __syncthreads();
  if (active && e == 0) {
    float v1 = -1e30f, v2 = -1e30f;
    int i1 = 0, i2 = 0;
#pragma unroll
    for (int q = 0; q < EE; q++) {
      float v = lg[sl][q];
      if (v > v1) { v2 = v1; i2 = i1; v1 = v; i1 = q; }
      else if (v > v2) { v2 = v; i2 = q; }
    }
    int t2 = toks[sl];
    float p = expf(v2 - v1);
    float sc = 1.0f / (1.0f + p);
    gate_e[t2 * 2] = i1;
    gate_e[t2 * 2 + 1] = i2;
    gate_w[t2 * 2] = sc;
    gate_w[t2 * 2 + 1] = p * sc;
  }
}

// ---------------- count: per-expert token counts from final gate_e ----------------
__global__ __launch_bounds__(256) void count_kernel(
    const int* __restrict__ gate_e, int* __restrict__ counts) {
  int t = blockIdx.x * 256 + threadIdx.x;
  if (t >= TT) return;
  atomicAdd(&counts[gate_e[t * 2]], 1);
  atomicAdd(&counts[gate_e[t * 2 + 1]], 1);
}

// ---------------- scan: offsets + tile map + slot_token init ----------------
__global__ __launch_bounds__(256) void scan_kernel(
    const int* __restrict__ counts, int* __restrict__ offs,
    int* __restrict__ tile_expert, int* __restrict__ ntiles,
    int* __restrict__ fill, int* __restrict__ slot_token) {
  int tid = threadIdx.x;
  for (int i = tid; i < NSLOT; i += 256) slot_token[i] = -1;
  if (tid == 0) {
    int off = 0, nt = 0;
    for (int e = 0; e < EE; e++) {
      offs[e] = off;
      fill[e] = 0;
      int tiles = (counts[e] + BM - 1) / BM;
      for (int t = 0; t < tiles; t++) tile_expert[nt++] = e;
      off += tiles * BM;
    }
    offs[EE] = off;
    ntiles[0] = nt;
  }
}

// ---------------- scatter tokens to slots ----------------
__global__ __launch_bounds__(256) void scatter_kernel(
    const int* __restrict__ gate_e, const float* __restrict__ gate_w,
    const int* __restrict__ offs, int* __restrict__ fill,
    int* __restrict__ slot_token, float* __restrict__ slot_w,
    int* __restrict__ slot_of) {
  int t = blockIdx.x * blockDim.x + threadIdx.x;
  if (t >= TT) return;
#pragma unroll
  for (int k = 0; k < 2; k++) {
    int e = gate_e[t * 2 + k];
    int pos = atomicAdd(&fill[e], 1);
    int slot = offs[e] + pos;
    slot_token[slot] = t;
    slot_w[slot] = gate_w[t * 2 + k];
    slot_of[t * 2 + k] = slot;
  }
}

// ---------------- GEMM1: h = gelu(x[slot] @ W1[e] + b1[e]) ----------------
__global__ __launch_bounds__(256) void gemm1_kernel(
    const unsigned short* __restrict__ xb, const unsigned short* __restrict__ w1t,
    const float* __restrict__ b1, const int* __restrict__ slot_token,
    const int* __restrict__ tile_expert, const int* __restrict__ ntiles,
    unsigned short* __restrict__ hb) {
  int mt = blockIdx.x;
  if (mt >= ntiles[0]) return;
  int e = tile_expert[mt];
  int row0 = mt * BM;
  int n0 = blockIdx.y * 128;
  __shared__ unsigned short As[128][32];
  __shared__ unsigned short Bs[128][32];
  int tid = threadIdx.x;
  int lane = tid & 63;
  int wave = tid >> 6;
  int wm = wave >> 1, wn = wave & 1;
  int ra = tid >> 2, c = tid & 3;
  int tok_a = slot_token[row0 + ra]; if (tok_a < 0) tok_a = 0;
  int tok_b = slot_token[row0 + ra + 64]; if (tok_b < 0) tok_b = 0;
  const unsigned short* wbase = w1t + ((size_t)e * HH * DD);
  f32x4 acc[4][4];
#pragma unroll
  for (int m = 0; m < 4; m++)
#pragma unroll
    for (int n = 0; n < 4; n++) {
      f32x4 z = {0.f, 0.f, 0.f, 0.f};
      acc[m][n] = z;
    }
  for (int kk = 0; kk < DD / 32; kk++) {
    int k0 = kk * 32;
    __syncthreads();
    gload16(xb + (size_t)tok_a * DD + k0 + c * 8, &As[ra][c * 8]);
    gload16(xb + (size_t)tok_b * DD + k0 + c * 8, &As[ra + 64][c * 8]);
    gload16(wbase + (size_t)(n0 + ra) * DD + k0 + c * 8, &Bs[ra][c * 8]);
    gload16(wbase + (size_t)(n0 + ra + 64) * DD + k0 + c * 8, &Bs[ra + 64][c * 8]);
    __syncthreads();
    bf16x8 a[4], b[4];
#pragma unroll
    for (int m = 0; m < 4; m++)
      a[m] = *(const bf16x8*)(&As[wm * 64 + m * 16 + (lane & 15)][(lane >> 4) * 8]);
#pragma unroll
    for (int n = 0; n < 4; n++)
      b[n] = *(const bf16x8*)(&Bs[wn * 64 + n * 16 + (lane & 15)][(lane >> 4) * 8]);
#pragma unroll
    for (int m = 0; m < 4; m++)
#pragma unroll
      for (int n = 0; n < 4; n++)
        acc[m][n] = __builtin_amdgcn_mfma_f32_16x16x32_bf16(a[m], b[n], acc[m][n], 0, 0, 0);
  }
  const float* b1e = b1 + (size_t)e * HH;
#pragma unroll
  for (int m = 0; m < 4; m++) {
#pragma unroll
    for (int r = 0; r < 4; r++) {
      int slot = row0 + wm * 64 + m * 16 + ((lane >> 4) << 2) + r;
      unsigned short* hrow = hb + (size_t)slot * HH;
#pragma unroll
      for (int n = 0; n < 4; n++) {
        int hc = n0 + wn * 64 + n * 16 + (lane & 15);
        float v = acc[m][n][r] + b1e[hc];
        v = 0.5f * v * (1.0f + erff(v * 0.70710678118654752f));
        hrow[hc] = f2bf(v);
      }
    }
  }
}

// ---------------- GEMM2: yw[slot] = w*(h[slot] @ W2[e] + b2[e]) ----------------
template <int USE_Y>
__global__ __launch_bounds__(256) void gemm2_kernel(
    const unsigned short* __restrict__ hb, const unsigned short* __restrict__ w2t,
    const float* __restrict__ b2, const int* __restrict__ slot_token,
    const float* __restrict__ slot_w, const int* __restrict__ tile_expert,
    const int* __restrict__ ntiles, unsigned short* __restrict__ yw,
    float* __restrict__ out) {
  int mt = blockIdx.x;
  if (mt >= ntiles[0]) return;
  int e = tile_expert[mt];
  int row0 = mt * BM;
  int n0 = blockIdx.y * 128;
  __shared__ unsigned short As[128][32];
  __shared__ unsigned short Bs[128][32];
  int tid = threadIdx.x;
  int lane = tid & 63;
  int wave = tid >> 6;
  int wm = wave >> 1, wn = wave & 1;
  int ra = tid >> 2, c = tid & 3;
  const unsigned short* wbase = w2t + ((size_t)e * DD * HH);
  f32x4 acc[4][4];
#pragma unroll
  for (int m = 0; m < 4; m++)
#pragma unroll
    for (int n = 0; n < 4; n++) {
      f32x4 z = {0.f, 0.f, 0.f, 0.f};
      acc[m][n] = z;
    }
  for (int kk = 0; kk < HH / 32; kk++) {
    int k0 = kk * 32;
    __syncthreads();
    gload16(hb + (size_t)(row0 + ra) * HH + k0 + c * 8, &As[ra][c * 8]);
    gload16(hb + (size_t)(row0 + ra + 64) * HH + k0 + c * 8, &As[ra + 64][c * 8]);
    gload16(wbase + (size_t)(n0 + ra) * HH + k0 + c * 8, &Bs[ra][c * 8]);
    gload16(wbase + (size_t)(n0 + ra + 64) * HH + k0 + c * 8, &Bs[ra + 64][c * 8]);
    __syncthreads();
    bf16x8 a[4], b[4];
#pragma unroll
    for (int m = 0; m < 4; m++)
      a[m] = *(const bf16x8*)(&As[wm * 64 + m * 16 + (lane & 15)][(lane >> 4) * 8]);
#pragma unroll
    for (int n = 0; n < 4; n++)
      b[n] = *(const bf16x8*)(&Bs[wn * 64 + n * 16 + (lane & 15)][(lane >> 4) * 8]);
#pragma unroll
    for (int m = 0; m < 4; m++)
#pragma unroll
      for (int n = 0; n < 4; n++)
        acc[m][n] = __builtin_amdgcn_mfma_f32_16x16x32_bf16(a[m], b[n], acc[m][n], 0, 0, 0);
  }
  const float* b2e = b2 + (size_t)e * DD;
#pragma unroll
  for (int m = 0; m < 4; m++) {
#pragma unroll
    for (int r = 0; r < 4; r++) {
      int slot = row0 + wm * 64 + m * 16 + ((lane >> 4) << 2) + r;
      if (USE_Y) {
        float w = slot_w[slot];
        unsigned short* yrow = yw + (size_t)slot * DD;
#pragma unroll
        for (int n = 0; n < 4; n++) {
          int dc = n0 + wn * 64 + n * 16 + (lane & 15);
          yrow[dc] = f2bf(w * (acc[m][n][r] + b2e[dc]));
        }
      } else {
        int tok = slot_token[slot];
        if (tok >= 0) {
          float w = slot_w[slot];
          float* orow = out + (size_t)tok * DD;
#pragma unroll
          for (int n = 0; n < 4; n++) {
            int dc = n0 + wn * 64 + n * 16 + (lane & 15);
            float v = acc[m][n][r] + b2e[dc];
            atomicAdd(&orow[dc], w * v);
          }
        }
      }
    }
  }
}

// ---------------- combine: out[t] = yw[s1] + yw[s2] ----------------
__global__ __launch_bounds__(256) void combine_kernel(
    const unsigned short* __restrict__ yw, const int* __restrict__ slot_of,
    float* __restrict__ out) {
  int gid = blockIdx.x * 256 + threadIdx.x;
  int t = gid >> 6;
  int d0 = (gid & 63) * 8;
  int s1 = slot_of[t * 2], s2 = slot_of[t * 2 + 1];
  const ushort4* p1 = (const ushort4*)(yw + (size_t)s1 * DD + d0);
  const ushort4* p2 = (const ushort4*)(yw + (size_t)s2 * DD + d0);
  ushort4 a0 = p1[0], a1 = p1[1];
  ushort4 b0 = p2[0], b1 = p2[1];
  float4 o0, o1;
  o0.x = bf2f(a0.x) + bf2f(b0.x);
  o0.y = bf2f(a0.y) + bf2f(b0.y);
  o0.z = bf2f(a0.z) + bf2f(b0.z);
  o0.w = bf2f(a0.w) + bf2f(b0.w);
  o1.x = bf2f(a1.x) + bf2f(b1.x);
  o1.y = bf2f(a1.y) + bf2f(b1.y);
  o1.z = bf2f(a1.z) + bf2f(b1.z);
  o1.w = bf2f(a1.w) + bf2f(b1.w);
  float* orow = out + (size_t)t * DD + d0;
  ((float4*)orow)[0] = o0;
  ((float4*)orow)[1] = o1;
}

extern "C" void kernel_launch(void* const* d_in, const int* in_sizes, int n_in,
                              void* d_out, int out_size, void* d_ws, size_t ws_size,
                              hipStream_t stream) {
  const float* x  = (const float*)d_in[0];
  const float* Wg = (const float*)d_in[1];
  const float* bg = (const float*)d_in[2];
  const float* W1 = (const float*)d_in[3];
  const float* b1 = (const float*)d_in[4];
  const float* W2 = (const float*)d_in[5];
  const float* b2 = (const float*)d_in[6];
  float* out = (float*)d_out;

  uint8_t* w = (uint8_t*)d_ws;
  size_t o = 0;
  unsigned short* xb  = (unsigned short*)(w + o); o += (size_t)TT * DD * 2;       // 8 MB
  unsigned short* w1t = (unsigned short*)(w + o); o += (size_t)EE * DD * HH * 2;  // 16 MB
  unsigned short* w2t = (unsigned short*)(w + o); o += (size_t)EE * DD * HH * 2;  // 16 MB
  unsigned short* hb  = (unsigned short*)(w + o); o += (size_t)NSLOT * HH * 2;    // 37.7 MB
  int*   slot_token = (int*)(w + o);   o += (size_t)NSLOT * 4;
  float* slot_w     = (float*)(w + o); o += (size_t)NSLOT * 4;
  int*   slot_of    = (int*)(w + o);   o += (size_t)TT * 2 * 4;
  int*   gate_e     = (int*)(w + o);   o += (size_t)TT * 2 * 4;
  float* gate_w     = (float*)(w + o); o += (size_t)TT * 2 * 4;
  int*   counts     = (int*)(w + o);   o += 64;
  int*   fill       = (int*)(w + o);   o += 64;
  int*   offs       = (int*)(w + o);   o += 128;
  int*   tile_expert= (int*)(w + o);   o += 640;
  int*   ntiles     = (int*)(w + o);   o += 64;
  int*   nretry     = (int*)(w + o);   o += 64;
  int*   retry      = (int*)(w + o);   o += RETRYCAP * 4;
  unsigned short* yw = (unsigned short*)(w + o);
  size_t need_y = o + (size_t)NSLOT * DD * 2;   // +18.9 MB
  int use_y = (ws_size >= need_y);

  hipMemsetAsync(counts, 0, 64, stream);
  hipMemsetAsync(nretry, 0, 64, stream);
  if (!use_y) hipMemsetAsync(d_out, 0, (size_t)TT * DD * 4, stream);

  // W1 [E][D][H] -> w1t [E][H][D]
  {
    dim3 g(HH / 64, DD / 64, EE);
    transpose_cv_kernel<<<g, 256, 0, stream>>>(W1, w1t, DD, HH);
  }
  // W2 [E][H][D] -> w2t [E][D][H]
  {
    dim3 g(DD / 64, HH / 64, EE);
    transpose_cv_kernel<<<g, 256, 0, stream>>>(W2, w2t, HH, DD);
  }
  gatecv_kernel<<<TT / 8, 256, 0, stream>>>(x, Wg, bg, xb, gate_e, gate_w,
                                            nretry, retry);
  gatefix_kernel<<<RETRYCAP / 16, 256, 0, stream>>>(x, Wg, bg, nretry, retry,
                                                    gate_e, gate_w);
  count_kernel<<<TT / 256, 256, 0, stream>>>(gate_e, counts);
  scan_kernel<<<1, 256, 0, stream>>>(counts, offs, tile_expert, ntiles, fill, slot_token);
  scatter_kernel<<<TT / 256, 256, 0, stream>>>(gate_e, gate_w, offs, fill,
                                               slot_token, slot_w, slot_of);
  {
    dim3 g(MAXTILES, HH / 128);
    gemm1_kernel<<<g, 256, 0, stream>>>(xb, w1t, b1, slot_token, tile_expert, ntiles, hb);
  }
  {
    dim3 g(MAXTILES, DD / 128);
    if (use_y)
      gemm2_kernel<1><<<g, 256, 0, stream>>>(hb, w2t, b2, slot_token, slot_w,
                                             tile_expert, ntiles, yw, out);
    else
      gemm2_kernel<0><<<g, 256, 0, stream>>>(hb, w2t, b2, slot_token, slot_w,
                                             tile_expert, ntiles, yw, out);
  }
  if (use_y) {
    combine_kernel<<<TT * (DD / 8) / 256, 256, 0, stream>>>(yw, slot_of, out);
  }
}

// Round 6
// 259.994 us; speedup vs baseline: 1.1364x; 1.0306x over previous
//
#include <hip/hip_runtime.h>
#include <hip/hip_bf16.h>
#include <math.h>

#define TT 8192
#define DD 512
#define HH 1024
#define EE 16
#define NSLOT 18432   // 144 * 128 max padded slots
#define MAXTILES 144
#define BM 128
#define RETRYCAP 1024

typedef __attribute__((ext_vector_type(8))) short bf16x8;
typedef __attribute__((ext_vector_type(4))) float f32x4;

__device__ __forceinline__ unsigned short f2bf(float f) {
  union { float f; unsigned u; } v; v.f = f;
  unsigned r = v.u + 0x7fffu + ((v.u >> 16) & 1u);
  return (unsigned short)(r >> 16);
}

__device__ __forceinline__ float bf2f(unsigned short u) {
  union { unsigned u; float f; } v; v.u = ((unsigned)u) << 16;
  return v.f;
}

__device__ __forceinline__ void gload16(const void* g, void* l) {
  __builtin_amdgcn_global_load_lds(
      (const __attribute__((address_space(1))) unsigned int*)g,
      (__attribute__((address_space(3))) unsigned int*)l, 16, 0, 0);
}

// ------- transpose+convert: in f32 [nmat][R][C] -> out bf16 [nmat][C][R] -------
__global__ __launch_bounds__(256) void transpose_cv_kernel(
    const float* __restrict__ in, unsigned short* __restrict__ out, int R, int C) {
  int mat = blockIdx.z;
  int c0 = blockIdx.x * 64;
  int r0 = blockIdx.y * 64;
  const float* src = in + (size_t)mat * R * C;
  unsigned short* dst = out + (size_t)mat * R * C;
  __shared__ unsigned short t[64][68];
  int tid = threadIdx.x;
#pragma unroll
  for (int p = 0; p < 4; p++) {
    int r = tid >> 2;
    int c4 = (tid & 3) + p * 4;
    float4 v = *(const float4*)(src + (size_t)(r0 + r) * C + c0 + c4 * 4);
    t[c4 * 4 + 0][r] = f2bf(v.x);
    t[c4 * 4 + 1][r] = f2bf(v.y);
    t[c4 * 4 + 2][r] = f2bf(v.z);
    t[c4 * 4 + 3][r] = f2bf(v.w);
  }
  __syncthreads();
#pragma unroll
  for (int p = 0; p < 4; p++) {
    int oc = (tid >> 4) + p * 16;
    int ch = tid & 15;
    ushort4 v = *(ushort4*)(&t[oc][ch * 4]);
    *(ushort4*)(dst + (size_t)(c0 + oc) * R + r0 + ch * 4) = v;
  }
}

// ---------------- fused convert + gate, f32 fast path ----------------
__global__ __launch_bounds__(256) void gatecv_kernel(
    const float* __restrict__ x, const float* __restrict__ Wg,
    const float* __restrict__ bg, unsigned short* __restrict__ xb,
    int* __restrict__ gate_e, float* __restrict__ gate_w,
    int* __restrict__ nretry, int* __restrict__ retry) {
  __shared__ float wg_s[DD][EE];   // 32 KB
  __shared__ float x_s[8][520];    // 16.25 KB
  int tid = threadIdx.x;
  int tok0 = blockIdx.x * 8;
#pragma unroll
  for (int p = 0; p < 8; p++) {
    int idx = p * 256 + tid;
    ((float4*)wg_s)[idx] = ((const float4*)Wg)[idx];
  }
#pragma unroll
  for (int p = 0; p < 4; p++) {
    int f = p * 256 + tid;
    float4 v = ((const float4*)(x + (size_t)tok0 * DD))[f];
    *(float4*)&x_s[f >> 7][(f & 127) * 4] = v;
    ushort4 u;
    u.x = f2bf(v.x); u.y = f2bf(v.y); u.z = f2bf(v.z); u.w = f2bf(v.w);
    ((ushort4*)(xb + (size_t)tok0 * DD))[f] = u;
  }
  __syncthreads();
  int wv = tid >> 6, lane = tid & 63;
  int e = lane & 15, tl = (lane >> 4) & 1, ck = lane >> 5;
  int t = wv * 2 + tl;
  const float* xr = &x_s[t][ck * 256];
  float a0 = 0.f, a1 = 0.f, a2 = 0.f, a3 = 0.f;
#pragma unroll 8
  for (int i = 0; i < 64; i++) {
    float4 xv = *(const float4*)&xr[i * 4];
    int d = ck * 256 + i * 4;
    a0 += xv.x * wg_s[d + 0][e];
    a1 += xv.y * wg_s[d + 1][e];
    a2 += xv.z * wg_s[d + 2][e];
    a3 += xv.w * wg_s[d + 3][e];
  }
  float acc = (a0 + a1) + (a2 + a3);
  acc += __shfl_xor(acc, 32);      // combine d-halves
  float lf = acc + bg[e];
  float v1 = -1e30f, v2 = -1e30f, v3 = -1e30f;
  int i1 = 0, i2 = 0;
#pragma unroll
  for (int q = 0; q < EE; q++) {
    float v = __shfl(lf, (lane & 16) | q);
    if (v > v1) { v3 = v2; v2 = v1; i2 = i1; v1 = v; i1 = q; }
    else if (v > v2) { v3 = v2; v2 = v; i2 = q; }
    else if (v > v3) { v3 = v; }
  }
  if (lane == 0 || lane == 16) {
    int t2 = tok0 + t;
    float p = expf(v2 - v1);
    float s = 1.0f / (1.0f + p);
    gate_e[t2 * 2] = i1;
    gate_e[t2 * 2 + 1] = i2;
    gate_w[t2 * 2] = s;
    gate_w[t2 * 2 + 1] = p * s;
    if (v2 - v3 < 1e-3f) {
      int pos = atomicAdd(nretry, 1);
      if (pos < RETRYCAP) retry[pos] = t2;
    }
  }
}

// ---------------- gatefix: exact f64 recompute for near-tie tokens ----------------
__global__ __launch_bounds__(256) void gatefix_kernel(
    const float* __restrict__ x, const float* __restrict__ Wg,
    const float* __restrict__ bg, const int* __restrict__ nretry,
    const int* __restrict__ retry, int* __restrict__ gate_e,
    float* __restrict__ gate_w) {
  __shared__ float lg[16][17];
  __shared__ int toks[16];
  int tid = threadIdx.x;
  int sl = tid >> 4, e = tid & 15;
  int s = blockIdx.x * 16 + sl;
  int n = *nretry; if (n > RETRYCAP) n = RETRYCAP;
  int active = (s < n);
  int tok = 0;
  if (active) tok = retry[s];
  if (active) {
    const float* xr = x + (size_t)tok * DD;
    double a0 = 0.0, a1 = 0.0, a2 = 0.0, a3 = 0.0;
    for (int i = 0; i < DD / 4; i++) {
      a0 += (double)xr[i * 4 + 0] * (double)Wg[(i * 4 + 0) * EE + e];
      a1 += (double)xr[i * 4 + 1] * (double)Wg[(i * 4 + 1) * EE + e];
      a2 += (double)xr[i * 4 + 2] * (double)Wg[(i * 4 + 2) * EE + e];
      a3 += (double)xr[i * 4 + 3] * (double)Wg[(i * 4 + 3) * EE + e];
    }
    double acc = (a0 + a1) + (a2 + a3);
    lg[sl][e] = (float)(acc + (double)bg[e]);
    toks[sl] = tok;
  }
  __syncthreads();
  if (active && e == 0) {
    float v1 = -1e30f, v2 = -1e30f;
    int i1 = 0, i2 = 0;
#pragma unroll
    for (int q = 0; q < EE; q++) {
      float v = lg[sl][q];
      if (v > v1) { v2 = v1; i2 = i1; v1 = v; i1 = q; }
      else if (v > v2) { v2 = v; i2 = q; }
    }
    int t2 = toks[sl];
    float p = expf(v2 - v1);
    float sc = 1.0f / (1.0f + p);
    gate_e[t2 * 2] = i1;
    gate_e[t2 * 2 + 1] = i2;
    gate_w[t2 * 2] = sc;
    gate_w[t2 * 2 + 1] = p * sc;
  }
}

// ---------------- count ----------------
__global__ __launch_bounds__(256) void count_kernel(
    const int* __restrict__ gate_e, int* __restrict__ counts) {
  int t = blockIdx.x * 256 + threadIdx.x;
  if (t >= TT) return;
  atomicAdd(&counts[gate_e[t * 2]], 1);
  atomicAdd(&counts[gate_e[t * 2 + 1]], 1);
}

// ---------------- scan ----------------
__global__ __launch_bounds__(256) void scan_kernel(
    const int* __restrict__ counts, int* __restrict__ offs,
    int* __restrict__ tile_expert, int* __restrict__ ntiles,
    int* __restrict__ fill, int* __restrict__ slot_token) {
  int tid = threadIdx.x;
  for (int i = tid; i < NSLOT; i += 256) slot_token[i] = -1;
  if (tid == 0) {
    int off = 0, nt = 0;
    for (int e = 0; e < EE; e++) {
      offs[e] = off;
      fill[e] = 0;
      int tiles = (counts[e] + BM - 1) / BM;
      for (int t = 0; t < tiles; t++) tile_expert[nt++] = e;
      off += tiles * BM;
    }
    offs[EE] = off;
    ntiles[0] = nt;
  }
}

// ---------------- scatter ----------------
__global__ __launch_bounds__(256) void scatter_kernel(
    const int* __restrict__ gate_e, const float* __restrict__ gate_w,
    const int* __restrict__ offs, int* __restrict__ fill,
    int* __restrict__ slot_token, float* __restrict__ slot_w,
    int* __restrict__ slot_of) {
  int t = blockIdx.x * blockDim.x + threadIdx.x;
  if (t >= TT) return;
#pragma unroll
  for (int k = 0; k < 2; k++) {
    int e = gate_e[t * 2 + k];
    int pos = atomicAdd(&fill[e], 1);
    int slot = offs[e] + pos;
    slot_token[slot] = t;
    slot_w[slot] = gate_w[t * 2 + k];
    slot_of[t * 2 + k] = slot;
  }
}

// ---------------- GEMM1: h = gelu(x[slot] @ W1[e] + b1[e]) ----------------
// Double-buffered LDS, prefetch next K-step before computing current
// (T3-minimum 2-phase). One barrier per K-step.
__global__ __launch_bounds__(256) void gemm1_kernel(
    const unsigned short* __restrict__ xb, const unsigned short* __restrict__ w1t,
    const float* __restrict__ b1, const int* __restrict__ slot_token,
    const int* __restrict__ tile_expert, const int* __restrict__ ntiles,
    unsigned short* __restrict__ hb) {
  int mt = blockIdx.x;
  if (mt >= ntiles[0]) return;
  int e = tile_expert[mt];
  int row0 = mt * BM;
  int n0 = blockIdx.y * 128;
  __shared__ unsigned short As[2][128][32];
  __shared__ unsigned short Bs[2][128][32];
  int tid = threadIdx.x;
  int lane = tid & 63;
  int wave = tid >> 6;
  int wm = wave >> 1, wn = wave & 1;
  int ra = tid >> 2, c = tid & 3;
  int tok_a = slot_token[row0 + ra]; if (tok_a < 0) tok_a = 0;
  int tok_b = slot_token[row0 + ra + 64]; if (tok_b < 0) tok_b = 0;
  const unsigned short* wbase = w1t + ((size_t)e * HH * DD);
  const unsigned short* ga0 = xb + (size_t)tok_a * DD + c * 8;
  const unsigned short* ga1 = xb + (size_t)tok_b * DD + c * 8;
  const unsigned short* gb0 = wbase + (size_t)(n0 + ra) * DD + c * 8;
  const unsigned short* gb1 = wbase + (size_t)(n0 + ra + 64) * DD + c * 8;
  f32x4 acc[4][4];
#pragma unroll
  for (int m = 0; m < 4; m++)
#pragma unroll
    for (int n = 0; n < 4; n++) {
      f32x4 z = {0.f, 0.f, 0.f, 0.f};
      acc[m][n] = z;
    }
  // prologue: stage k0=0 into buffer 0
  gload16(ga0, &As[0][ra][c * 8]);
  gload16(ga1, &As[0][ra + 64][c * 8]);
  gload16(gb0, &Bs[0][ra][c * 8]);
  gload16(gb1, &Bs[0][ra + 64][c * 8]);
  __syncthreads();
  int cur = 0;
  for (int kk = 0; kk < DD / 32; kk++) {
    if (kk + 1 < DD / 32) {
      int k1 = (kk + 1) * 32;
      int nx = cur ^ 1;
      gload16(ga0 + k1, &As[nx][ra][c * 8]);
      gload16(ga1 + k1, &As[nx][ra + 64][c * 8]);
      gload16(gb0 + k1, &Bs[nx][ra][c * 8]);
      gload16(gb1 + k1, &Bs[nx][ra + 64][c * 8]);
    }
    bf16x8 a[4], b[4];
#pragma unroll
    for (int m = 0; m < 4; m++)
      a[m] = *(const bf16x8*)(&As[cur][wm * 64 + m * 16 + (lane & 15)][(lane >> 4) * 8]);
#pragma unroll
    for (int n = 0; n < 4; n++)
      b[n] = *(const bf16x8*)(&Bs[cur][wn * 64 + n * 16 + (lane & 15)][(lane >> 4) * 8]);
#pragma unroll
    for (int m = 0; m < 4; m++)
#pragma unroll
      for (int n = 0; n < 4; n++)
        acc[m][n] = __builtin_amdgcn_mfma_f32_16x16x32_bf16(a[m], b[n], acc[m][n], 0, 0, 0);
    __syncthreads();   // drains prefetch (vmcnt) + recycles buffer
    cur ^= 1;
  }
  const float* b1e = b1 + (size_t)e * HH;
#pragma unroll
  for (int m = 0; m < 4; m++) {
#pragma unroll
    for (int r = 0; r < 4; r++) {
      int slot = row0 + wm * 64 + m * 16 + ((lane >> 4) << 2) + r;
      unsigned short* hrow = hb + (size_t)slot * HH;
#pragma unroll
      for (int n = 0; n < 4; n++) {
        int hc = n0 + wn * 64 + n * 16 + (lane & 15);
        float v = acc[m][n][r] + b1e[hc];
        v = 0.5f * v * (1.0f + erff(v * 0.70710678118654752f));
        hrow[hc] = f2bf(v);
      }
    }
  }
}

// ---------------- GEMM2: yw[slot] = w*(h[slot] @ W2[e] + b2[e]) ----------------
template <int USE_Y>
__global__ __launch_bounds__(256) void gemm2_kernel(
    const unsigned short* __restrict__ hb, const unsigned short* __restrict__ w2t,
    const float* __restrict__ b2, const int* __restrict__ slot_token,
    const float* __restrict__ slot_w, const int* __restrict__ tile_expert,
    const int* __restrict__ ntiles, unsigned short* __restrict__ yw,
    float* __restrict__ out) {
  int mt = blockIdx.x;
  if (mt >= ntiles[0]) return;
  int e = tile_expert[mt];
  int row0 = mt * BM;
  int n0 = blockIdx.y * 128;
  __shared__ unsigned short As[2][128][32];
  __shared__ unsigned short Bs[2][128][32];
  int tid = threadIdx.x;
  int lane = tid & 63;
  int wave = tid >> 6;
  int wm = wave >> 1, wn = wave & 1;
  int ra = tid >> 2, c = tid & 3;
  const unsigned short* wbase = w2t + ((size_t)e * DD * HH);
  const unsigned short* ga0 = hb + (size_t)(row0 + ra) * HH + c * 8;
  const unsigned short* ga1 = hb + (size_t)(row0 + ra + 64) * HH + c * 8;
  const unsigned short* gb0 = wbase + (size_t)(n0 + ra) * HH + c * 8;
  const unsigned short* gb1 = wbase + (size_t)(n0 + ra + 64) * HH + c * 8;
  f32x4 acc[4][4];
#pragma unroll
  for (int m = 0; m < 4; m++)
#pragma unroll
    for (int n = 0; n < 4; n++) {
      f32x4 z = {0.f, 0.f, 0.f, 0.f};
      acc[m][n] = z;
    }
  gload16(ga0, &As[0][ra][c * 8]);
  gload16(ga1, &As[0][ra + 64][c * 8]);
  gload16(gb0, &Bs[0][ra][c * 8]);
  gload16(gb1, &Bs[0][ra + 64][c * 8]);
  __syncthreads();
  int cur = 0;
  for (int kk = 0; kk < HH / 32; kk++) {
    if (kk + 1 < HH / 32) {
      int k1 = (kk + 1) * 32;
      int nx = cur ^ 1;
      gload16(ga0 + k1, &As[nx][ra][c * 8]);
      gload16(ga1 + k1, &As[nx][ra + 64][c * 8]);
      gload16(gb0 + k1, &Bs[nx][ra][c * 8]);
      gload16(gb1 + k1, &Bs[nx][ra + 64][c * 8]);
    }
    bf16x8 a[4], b[4];
#pragma unroll
    for (int m = 0; m < 4; m++)
      a[m] = *(const bf16x8*)(&As[cur][wm * 64 + m * 16 + (lane & 15)][(lane >> 4) * 8]);
#pragma unroll
    for (int n = 0; n < 4; n++)
      b[n] = *(const bf16x8*)(&Bs[cur][wn * 64 + n * 16 + (lane & 15)][(lane >> 4) * 8]);
#pragma unroll
    for (int m = 0; m < 4; m++)
#pragma unroll
      for (int n = 0; n < 4; n++)
        acc[m][n] = __builtin_amdgcn_mfma_f32_16x16x32_bf16(a[m], b[n], acc[m][n], 0, 0, 0);
    __syncthreads();
    cur ^= 1;
  }
  const float* b2e = b2 + (size_t)e * DD;
#pragma unroll
  for (int m = 0; m < 4; m++) {
#pragma unroll
    for (int r = 0; r < 4; r++) {
      int slot = row0 + wm * 64 + m * 16 + ((lane >> 4) << 2) + r;
      if (USE_Y) {
        float w = slot_w[slot];
        unsigned short* yrow = yw + (size_t)slot * DD;
#pragma unroll
        for (int n = 0; n < 4; n++) {
          int dc = n0 + wn * 64 + n * 16 + (lane & 15);
          yrow[dc] = f2bf(w * (acc[m][n][r] + b2e[dc]));
        }
      } else {
        int tok = slot_token[slot];
        if (tok >= 0) {
          float w = slot_w[slot];
          float* orow = out + (size_t)tok * DD;
#pragma unroll
          for (int n = 0; n < 4; n++) {
            int dc = n0 + wn * 64 + n * 16 + (lane & 15);
            float v = acc[m][n][r] + b2e[dc];
            atomicAdd(&orow[dc], w * v);
          }
        }
      }
    }
  }
}

// ---------------- combine: out[t] = yw[s1] + yw[s2] ----------------
__global__ __launch_bounds__(256) void combine_kernel(
    const unsigned short* __restrict__ yw, const int* __restrict__ slot_of,
    float* __restrict__ out) {
  int gid = blockIdx.x * 256 + threadIdx.x;
  int t = gid >> 6;
  int d0 = (gid & 63) * 8;
  int s1 = slot_of[t * 2], s2 = slot_of[t * 2 + 1];
  const ushort4* p1 = (const ushort4*)(yw + (size_t)s1 * DD + d0);
  const ushort4* p2 = (const ushort4*)(yw + (size_t)s2 * DD + d0);
  ushort4 a0 = p1[0], a1 = p1[1];
  ushort4 b0 = p2[0], b1 = p2[1];
  float4 o0, o1;
  o0.x = bf2f(a0.x) + bf2f(b0.x);
  o0.y = bf2f(a0.y) + bf2f(b0.y);
  o0.z = bf2f(a0.z) + bf2f(b0.z);
  o0.w = bf2f(a0.w) + bf2f(b0.w);
  o1.x = bf2f(a1.x) + bf2f(b1.x);
  o1.y = bf2f(a1.y) + bf2f(b1.y);
  o1.z = bf2f(a1.z) + bf2f(b1.z);
  o1.w = bf2f(a1.w) + bf2f(b1.w);
  float* orow = out + (size_t)t * DD + d0;
  ((float4*)orow)[0] = o0;
  ((float4*)orow)[1] = o1;
}

extern "C" void kernel_launch(void* const* d_in, const int* in_sizes, int n_in,
                              void* d_out, int out_size, void* d_ws, size_t ws_size,
                              hipStream_t stream) {
  const float* x  = (const float*)d_in[0];
  const float* Wg = (const float*)d_in[1];
  const float* bg = (const float*)d_in[2];
  const float* W1 = (const float*)d_in[3];
  const float* b1 = (const float*)d_in[4];
  const float* W2 = (const float*)d_in[5];
  const float* b2 = (const float*)d_in[6];
  float* out = (float*)d_out;

  uint8_t* w = (uint8_t*)d_ws;
  size_t o = 0;
  unsigned short* xb  = (unsigned short*)(w + o); o += (size_t)TT * DD * 2;       // 8 MB
  unsigned short* w1t = (unsigned short*)(w + o); o += (size_t)EE * DD * HH * 2;  // 16 MB
  unsigned short* w2t = (unsigned short*)(w + o); o += (size_t)EE * DD * HH * 2;  // 16 MB
  unsigned short* hb  = (unsigned short*)(w + o); o += (size_t)NSLOT * HH * 2;    // 37.7 MB
  int*   slot_token = (int*)(w + o);   o += (size_t)NSLOT * 4;
  float* slot_w     = (float*)(w + o); o += (size_t)NSLOT * 4;
  int*   slot_of    = (int*)(w + o);   o += (size_t)TT * 2 * 4;
  int*   gate_e     = (int*)(w + o);   o += (size_t)TT * 2 * 4;
  float* gate_w     = (float*)(w + o); o += (size_t)TT * 2 * 4;
  int*   counts     = (int*)(w + o);   o += 64;
  int*   fill       = (int*)(w + o);   o += 64;
  int*   offs       = (int*)(w + o);   o += 128;
  int*   tile_expert= (int*)(w + o);   o += 640;
  int*   ntiles     = (int*)(w + o);   o += 64;
  int*   nretry     = (int*)(w + o);   o += 64;
  int*   retry      = (int*)(w + o);   o += RETRYCAP * 4;
  unsigned short* yw = (unsigned short*)(w + o);
  size_t need_y = o + (size_t)NSLOT * DD * 2;   // +18.9 MB
  int use_y = (ws_size >= need_y);

  hipMemsetAsync(counts, 0, 64, stream);
  hipMemsetAsync(nretry, 0, 64, stream);
  if (!use_y) hipMemsetAsync(d_out, 0, (size_t)TT * DD * 4, stream);

  // W1 [E][D][H] -> w1t [E][H][D]
  {
    dim3 g(HH / 64, DD / 64, EE);
    transpose_cv_kernel<<<g, 256, 0, stream>>>(W1, w1t, DD, HH);
  }
  // W2 [E][H][D] -> w2t [E][D][H]
  {
    dim3 g(DD / 64, HH / 64, EE);
    transpose_cv_kernel<<<g, 256, 0, stream>>>(W2, w2t, HH, DD);
  }
  gatecv_kernel<<<TT / 8, 256, 0, stream>>>(x, Wg, bg, xb, gate_e, gate_w,
                                            nretry, retry);
  gatefix_kernel<<<RETRYCAP / 16, 256, 0, stream>>>(x, Wg, bg, nretry, retry,
                                                    gate_e, gate_w);
  count_kernel<<<TT / 256, 256, 0, stream>>>(gate_e, counts);
  scan_kernel<<<1, 256, 0, stream>>>(counts, offs, tile_expert, ntiles, fill, slot_token);
  scatter_kernel<<<TT / 256, 256, 0, stream>>>(gate_e, gate_w, offs, fill,
                                               slot_token, slot_w, slot_of);
  {
    dim3 g(MAXTILES, HH / 128);
    gemm1_kernel<<<g, 256, 0, stream>>>(xb, w1t, b1, slot_token, tile_expert, ntiles, hb);
  }
  {
    dim3 g(MAXTILES, DD / 128);
    if (use_y)
      gemm2_kernel<1><<<g, 256, 0, stream>>>(hb, w2t, b2, slot_token, slot_w,
                                             tile_expert, ntiles, yw, out);
    else
      gemm2_kernel<0><<<g, 256, 0, stream>>>(hb, w2t, b2, slot_token, slot_w,
                                             tile_expert, ntiles, yw, out);
  }
  if (use_y) {
    combine_kernel<<<TT * (DD / 8) / 256, 256, 0, stream>>>(yw, slot_of, out);
  }
}